// Round 9
// baseline (261.881 us; speedup 1.0000x reference)
//
#include <hip/hip_runtime.h>
#include <hip/hip_fp16.h>

#define NN 100000
#define NE 1600000
#define NB 782            // dst buckets of 128 nodes: ceil(NN/128)
#define EPB 2048          // edges per block in bucket phases
#define NBLK_A 782        // ceil(NE/EPB)
#define SCNT (NB * NBLK_A)             // 611524 (divisible by 4)
#define SC_NB ((SCNT + 1023) / 1024)   // 598
#define CAP 4096          // bucket capacity for LDS staging (mean 2046, sd ~45)

// ---------------- CSR build: atomic-light bucketing ----------------

__global__ void bhistA_kernel(const int* __restrict__ dst, int* __restrict__ histT) {
    __shared__ int hist[NB];
    int t = threadIdx.x, b = blockIdx.x;
    for (int i = t; i < NB; i += 256) hist[i] = 0;
    __syncthreads();
    int e0 = b * EPB + t * 4;
#pragma unroll
    for (int half = 0; half < 2; ++half) {
        int e = e0 + half * 1024;
        if (e < NE) {   // NE%4==0 && e%4==0 -> e+3 in bounds
            int4 d4 = *(const int4*)(dst + e);
            atomicAdd(&hist[d4.x >> 7], 1);
            atomicAdd(&hist[d4.y >> 7], 1);
            atomicAdd(&hist[d4.z >> 7], 1);
            atomicAdd(&hist[d4.w >> 7], 1);
        }
    }
    __syncthreads();
    for (int i = t; i < NB; i += 256) histT[i * NBLK_A + b] = hist[i];
}

__global__ void scan1g_kernel(const int* __restrict__ in, int* __restrict__ out,
                              int* __restrict__ blkSum) {
    __shared__ int ts[256];
    int t = threadIdx.x, b = blockIdx.x;
    int base = b * 1024 + t * 4;
    int4 c = {0, 0, 0, 0};
    if (base < SCNT) c = *(const int4*)(in + base);
    int s = c.x + c.y + c.z + c.w;
    ts[t] = s;
    __syncthreads();
    for (int ofs = 1; ofs < 256; ofs <<= 1) {
        int v = (t >= ofs) ? ts[t - ofs] : 0;
        __syncthreads();
        ts[t] += v;
        __syncthreads();
    }
    if (t == 255) blkSum[b] = ts[255];
    int ex = ts[t] - s;
    if (base < SCNT) {
        int4 p;
        p.x = ex; p.y = ex + c.x; p.z = p.y + c.y; p.w = p.z + c.z;
        *(int4*)(out + base) = p;
    }
}

__global__ void scan2g_kernel(int* __restrict__ blkSum) {  // SC_NB <= 1024
    __shared__ int ts[1024];
    int t = threadIdx.x;
    int v = (t < SC_NB) ? blkSum[t] : 0;
    ts[t] = v;
    __syncthreads();
    for (int ofs = 1; ofs < 1024; ofs <<= 1) {
        int u = (t >= ofs) ? ts[t - ofs] : 0;
        __syncthreads();
        ts[t] += u;
        __syncthreads();
    }
    if (t < SC_NB) blkSum[t] = ts[t] - v;
}

// Scatter packed (src | local_dst<<20); cursors = partial scan + folded block offset.
__global__ void bscatB_kernel(const int* __restrict__ src, const int* __restrict__ dst,
                              const int* __restrict__ scanT, const int* __restrict__ blkSum,
                              int* __restrict__ ebuf) {
    __shared__ int cur[NB];
    int t = threadIdx.x, b = blockIdx.x;
    for (int i = t; i < NB; i += 256) {
        int idx = i * NBLK_A + b;
        cur[i] = scanT[idx] + blkSum[idx >> 10];
    }
    __syncthreads();
    int e0 = b * EPB + t * 4;
#pragma unroll
    for (int half = 0; half < 2; ++half) {
        int e = e0 + half * 1024;
        if (e < NE) {
            int4 d4 = *(const int4*)(dst + e);
            int4 s4 = *(const int4*)(src + e);
            int p0 = atomicAdd(&cur[d4.x >> 7], 1);
            ebuf[p0] = s4.x | ((d4.x & 127) << 20);
            int p1 = atomicAdd(&cur[d4.y >> 7], 1);
            ebuf[p1] = s4.y | ((d4.y & 127) << 20);
            int p2 = atomicAdd(&cur[d4.z >> 7], 1);
            ebuf[p2] = s4.z | ((d4.z & 127) << 20);
            int p3 = atomicAdd(&cur[d4.w >> 7], 1);
            ebuf[p3] = s4.w | ((d4.w & 127) << 20);
        }
    }
}

// Per-bucket CSR finalize (offset folded from blkSum).
__global__ void csrC_kernel(const int* __restrict__ ebuf, const int* __restrict__ scanT,
                            const int* __restrict__ blkSum,
                            int* __restrict__ row_ptr, int* __restrict__ col,
                            float* __restrict__ dinv) {
    __shared__ int es[CAP];
    __shared__ int hist[128];
    __shared__ int ts[128];
    __shared__ int cur[128];
    int t = threadIdx.x, b = blockIdx.x;
    int i0 = b * NBLK_A;
    int base = scanT[i0] + blkSum[i0 >> 10];
    int end;
    if (b + 1 < NB) {
        int i1 = (b + 1) * NBLK_A;
        end = scanT[i1] + blkSum[i1 >> 10];
    } else {
        end = NE;
    }
    int cnt = end - base;
    if (t < 128) hist[t] = 0;
    __syncthreads();
    for (int i = t; i < cnt; i += 256) {
        int e = ebuf[base + i];
        if (i < CAP) es[i] = e;
        atomicAdd(&hist[e >> 20], 1);
    }
    __syncthreads();
    if (t < 128) ts[t] = hist[t];
    __syncthreads();
    for (int ofs = 1; ofs < 128; ofs <<= 1) {
        int v = 0;
        if (t < 128 && t >= ofs) v = ts[t - ofs];
        __syncthreads();
        if (t < 128) ts[t] += v;
        __syncthreads();
    }
    if (t < 128) {
        int ex = ts[t] - hist[t];
        cur[t] = ex;
        int g = b * 128 + t;
        if (g < NN) {
            row_ptr[g] = base + ex;
            dinv[g] = rsqrtf((float)hist[t] + 1.0f);
        }
    }
    if (b == 0 && t == 0) row_ptr[NN] = NE;
    __syncthreads();
    for (int i = t; i < cnt; i += 256) {
        int e = (i < CAP) ? es[i] : ebuf[base + i];
        int r = atomicAdd(&cur[e >> 20], 1);  // LDS atomic
        col[base + r] = e & 0xFFFFF;
    }
}

// ---------------- helpers ----------------

__device__ inline ushort4 f4_to_h4(float4 v) {
    ushort4 o;
    o.x = __half_as_ushort(__float2half(v.x));
    o.y = __half_as_ushort(__float2half(v.y));
    o.z = __half_as_ushort(__float2half(v.z));
    o.w = __half_as_ushort(__float2half(v.w));
    return o;
}

// q[i,c] = fp16(dinv[i] * x[i,c])
template<int C>
__global__ void quant_kernel(const float4* __restrict__ x, const float* __restrict__ dinv,
                             ushort4* __restrict__ q) {
    constexpr int TPN = C / 4;
    int gid = blockIdx.x * blockDim.x + threadIdx.x;
    if (gid >= NN * TPN) return;
    int node = gid / TPN;
    float d = dinv[node];
    float4 v = x[gid];
    v.x *= d; v.y *= d; v.z *= d; v.w *= d;
    q[gid] = f4_to_h4(v);
}

// ---------------- register-tiled matmul ----------------
template<int IN, int OUT, bool RELU, bool HASBIAS, bool QUANT>
__global__ void mm_kernel(const float* __restrict__ x, const float* __restrict__ W,
                          const float* __restrict__ bias, const float* __restrict__ dinv,
                          float4* __restrict__ out, ushort4* __restrict__ qout) {
    constexpr int CG   = OUT / 4;      // col groups: 8,16,32
    constexpr int RG   = 256 / CG;     // row groups: 32,16,8
    constexpr int ROWS = RG * 4;       // rows per block: 128,64,32
    constexpr int P    = IN + 4;       // padded x pitch
    __shared__ float4 Ws[IN * CG];
    __shared__ float  xs[ROWS * P];

    int tid = threadIdx.x;
    const float4* W4 = (const float4*)W;
    for (int i = tid; i < IN * CG; i += 256) Ws[i] = W4[i];

    int n0 = blockIdx.x * ROWS;
    for (int i = tid; i < ROWS * IN; i += 256) {
        int r = i / IN, c = i & (IN - 1);
        size_t g = (size_t)n0 * IN + i;
        if (g < (size_t)NN * IN) xs[r * P + c] = x[g];
    }
    __syncthreads();

    int cg = tid % CG;
    int rg = tid / CG;

    float4 acc[4] = {{0,0,0,0},{0,0,0,0},{0,0,0,0},{0,0,0,0}};
#pragma unroll 2
    for (int k = 0; k < IN; k += 4) {
        float4 w0 = Ws[(k + 0) * CG + cg];
        float4 w1 = Ws[(k + 1) * CG + cg];
        float4 w2 = Ws[(k + 2) * CG + cg];
        float4 w3 = Ws[(k + 3) * CG + cg];
#pragma unroll
        for (int i = 0; i < 4; ++i) {
            float4 xq = *(const float4*)&xs[(i * RG + rg) * P + k];
            acc[i].x = fmaf(xq.x, w0.x, acc[i].x);
            acc[i].y = fmaf(xq.x, w0.y, acc[i].y);
            acc[i].z = fmaf(xq.x, w0.z, acc[i].z);
            acc[i].w = fmaf(xq.x, w0.w, acc[i].w);
            acc[i].x = fmaf(xq.y, w1.x, acc[i].x);
            acc[i].y = fmaf(xq.y, w1.y, acc[i].y);
            acc[i].z = fmaf(xq.y, w1.z, acc[i].z);
            acc[i].w = fmaf(xq.y, w1.w, acc[i].w);
            acc[i].x = fmaf(xq.z, w2.x, acc[i].x);
            acc[i].y = fmaf(xq.z, w2.y, acc[i].y);
            acc[i].z = fmaf(xq.z, w2.z, acc[i].z);
            acc[i].w = fmaf(xq.z, w2.w, acc[i].w);
            acc[i].x = fmaf(xq.w, w3.x, acc[i].x);
            acc[i].y = fmaf(xq.w, w3.y, acc[i].y);
            acc[i].z = fmaf(xq.w, w3.z, acc[i].z);
            acc[i].w = fmaf(xq.w, w3.w, acc[i].w);
        }
    }

    float4 bb = {0, 0, 0, 0};
    if (HASBIAS) bb = ((const float4*)bias)[cg];
#pragma unroll
    for (int i = 0; i < 4; ++i) {
        int node = n0 + i * RG + rg;
        if (node >= NN) continue;
        float4 r = acc[i];
        if (HASBIAS) { r.x += bb.x; r.y += bb.y; r.z += bb.z; r.w += bb.w; }
        if (RELU) {
            r.x = fmaxf(r.x, 0.f); r.y = fmaxf(r.y, 0.f);
            r.z = fmaxf(r.z, 0.f); r.w = fmaxf(r.w, 0.f);
        }
        if (QUANT) {
            float d = dinv[node];
            r.x *= d; r.y *= d; r.z *= d; r.w *= d;
            qout[(size_t)node * CG + cg] = f4_to_h4(r);
        } else {
            out[(size_t)node * CG + cg] = r;
        }
    }
}

// ---------------- aggregate (fp16 gather, f32 accum, int4 col loads) ----------------

__device__ inline void acc8(float* a, uint4 u) {
    const __half2* hp = (const __half2*)&u;
#pragma unroll
    for (int q = 0; q < 4; ++q) {
        float2 f = __half22float2(hp[q]);
        a[2 * q]     += f.x;
        a[2 * q + 1] += f.y;
    }
}

template<int C, bool BIASRELU, bool WRITE_Q>
__global__ void agg_kernel(const uint4* __restrict__ h, const int* __restrict__ row_ptr,
                           const int* __restrict__ col, const float* __restrict__ dinv,
                           const float* __restrict__ b, float4* __restrict__ out,
                           uint4* __restrict__ qout) {
    constexpr int TPN = C / 8;
    int gid = blockIdx.x * blockDim.x + threadIdx.x;
    int node = gid / TPN;
    int cg = gid % TPN;
    if (node >= NN) return;
    int beg = row_ptr[node];
    int end = row_ptr[node + 1];

    float a[8] = {0, 0, 0, 0, 0, 0, 0, 0};
    acc8(a, h[(size_t)node * TPN + cg]);  // self-loop term

    int j = beg;
    // align j to 4 for int4 col loads
    for (; j < end && (j & 3); ++j) acc8(a, h[(size_t)col[j] * TPN + cg]);
    // 8 edges per iteration: 2 int4 col loads, 8 gathers in flight
    for (; j + 8 <= end; j += 8) {
        int4 c0 = *(const int4*)(col + j);
        int4 c1 = *(const int4*)(col + j + 4);
        uint4 u0 = h[(size_t)c0.x * TPN + cg];
        uint4 u1 = h[(size_t)c0.y * TPN + cg];
        uint4 u2 = h[(size_t)c0.z * TPN + cg];
        uint4 u3 = h[(size_t)c0.w * TPN + cg];
        uint4 u4 = h[(size_t)c1.x * TPN + cg];
        uint4 u5 = h[(size_t)c1.y * TPN + cg];
        uint4 u6 = h[(size_t)c1.z * TPN + cg];
        uint4 u7 = h[(size_t)c1.w * TPN + cg];
        acc8(a, u0); acc8(a, u1); acc8(a, u2); acc8(a, u3);
        acc8(a, u4); acc8(a, u5); acc8(a, u6); acc8(a, u7);
    }
    for (; j + 4 <= end; j += 4) {
        int4 c0 = *(const int4*)(col + j);
        uint4 u0 = h[(size_t)c0.x * TPN + cg];
        uint4 u1 = h[(size_t)c0.y * TPN + cg];
        uint4 u2 = h[(size_t)c0.z * TPN + cg];
        uint4 u3 = h[(size_t)c0.w * TPN + cg];
        acc8(a, u0); acc8(a, u1); acc8(a, u2); acc8(a, u3);
    }
    for (; j < end; ++j) acc8(a, h[(size_t)col[j] * TPN + cg]);

    float d = dinv[node];
    float r[8];
    if (BIASRELU) {
        const float* bp = b + cg * 8;
#pragma unroll
        for (int q = 0; q < 8; ++q) r[q] = fmaxf(fmaf(d, a[q], bp[q]), 0.f);
    } else {
#pragma unroll
        for (int q = 0; q < 8; ++q) r[q] = d * a[q];
    }
    float4* op = out + (size_t)node * (C / 4) + cg * 2;
    op[0] = make_float4(r[0], r[1], r[2], r[3]);
    op[1] = make_float4(r[4], r[5], r[6], r[7]);
    if (WRITE_Q) {
        uint4 qv;
        __half2* qp = (__half2*)&qv;
#pragma unroll
        for (int q = 0; q < 4; ++q)
            qp[q] = __float22half2_rn(make_float2(r[2 * q] * d, r[2 * q + 1] * d));
        qout[(size_t)node * TPN + cg] = qv;
    }
}

// ---------------- launch ----------------

extern "C" void kernel_launch(void* const* d_in, const int* in_sizes, int n_in,
                              void* d_out, int out_size, void* d_ws, size_t ws_size,
                              hipStream_t stream) {
    const int* ei = (const int*)d_in[0];
    const int* src = ei;
    const int* dst = ei + NE;
    const float* emb = (const float*)d_in[1];
    const float* We1 = (const float*)d_in[2]; const float* be1 = (const float*)d_in[3];
    const float* We2 = (const float*)d_in[4]; const float* be2 = (const float*)d_in[5];
    const float* Wd1 = (const float*)d_in[6]; const float* bd1 = (const float*)d_in[7];
    const float* Wd2 = (const float*)d_in[8]; const float* bd2 = (const float*)d_in[9];

    float* outp  = (float*)d_out;
    float* recon = outp;                      // [NN*128]
    float* z     = outp + (size_t)NN * 128;   // [NN*32]

    char* ws = (char*)d_ws;
    size_t off = 0;
    auto alloc = [&](size_t bytes) {
        void* p = ws + off;
        off += (bytes + 255) & ~(size_t)255;
        return p;
    };
    int*     row_ptr = (int*)    alloc((size_t)(NN + 1) * 4);
    int*     col     = (int*)    alloc((size_t)NE * 4);
    float*   dinv    = (float*)  alloc((size_t)NN * 4);
    int*     histT   = (int*)    alloc((size_t)SCNT * 4);
    int*     scanT   = (int*)    alloc((size_t)SCNT * 4);
    int*     blkSum  = (int*)    alloc((size_t)SC_NB * 4);
    void*    region1 = alloc((size_t)NN * 32 * 4);         // ebuf (NE*4=6.4MB) / fA (12.8MB)
    ushort4* qA      = (ushort4*)alloc((size_t)NN * 64 * 2);
    ushort4* qB      = (ushort4*)alloc((size_t)NN * 64 * 2);
    float*   fB      = (float*)  alloc((size_t)NN * 64 * 4);
    int*     ebuf    = (int*)region1;
    float*   fA      = (float*)region1;   // alive only after CSR build done
    (void)ws_size; (void)in_sizes; (void)n_in; (void)out_size;

    // --- CSR build (bucketed, no global atomics, scan3 folded) ---
    bhistA_kernel<<<NBLK_A, 256, 0, stream>>>(dst, histT);
    scan1g_kernel<<<SC_NB, 256, 0, stream>>>(histT, scanT, blkSum);
    scan2g_kernel<<<1, 1024, 0, stream>>>(blkSum);
    bscatB_kernel<<<NBLK_A, 256, 0, stream>>>(src, dst, scanT, blkSum, ebuf);
    csrC_kernel<<<NB, 256, 0, stream>>>(ebuf, scanT, blkSum, row_ptr, col, dinv);

    // --- layer 1 (agg-first): q1 = fp16(dinv*emb); a1 = dinv*(q1+Σ); x1 = relu(a1@We1+be1) ---
    quant_kernel<32><<<(NN * 8 + 255) / 256, 256, 0, stream>>>((const float4*)emb, dinv, qA);
    agg_kernel<32, false, false><<<(NN * 4 + 255) / 256, 256, 0, stream>>>(
        (const uint4*)qA, row_ptr, col, dinv, nullptr, (float4*)fA, nullptr);
    mm_kernel<32, 64, true, true, false><<<(NN + 63) / 64, 256, 0, stream>>>(
        fA, We1, be1, dinv, (float4*)fB, nullptr);

    // --- layer 2 (transform-first): h2 = fp16(dinv*(x1@We2)); z = relu(dinv*(h2+Σ)+be2); q3 = fp16(dinv*z) ---
    mm_kernel<64, 32, false, false, true><<<(NN + 127) / 128, 256, 0, stream>>>(
        fB, We2, nullptr, dinv, nullptr, qB);
    agg_kernel<32, true, true><<<(NN * 4 + 255) / 256, 256, 0, stream>>>(
        (const uint4*)qB, row_ptr, col, dinv, be2, (float4*)z, (uint4*)qA);

    // --- layer 3 (agg-first): a3 = dinv*(q3+Σ); q4 = fp16(dinv*relu(a3@Wd1+bd1)) ---
    agg_kernel<32, false, false><<<(NN * 4 + 255) / 256, 256, 0, stream>>>(
        (const uint4*)qA, row_ptr, col, dinv, nullptr, (float4*)fA, nullptr);
    mm_kernel<32, 64, true, true, true><<<(NN + 63) / 64, 256, 0, stream>>>(
        fA, Wd1, bd1, dinv, nullptr, qB);

    // --- layer 4 (agg-first): a4 = dinv*(q4+Σ); recon = a4@Wd2+bd2 ---
    agg_kernel<64, false, false><<<(NN * 8 + 255) / 256, 256, 0, stream>>>(
        (const uint4*)qB, row_ptr, col, dinv, nullptr, (float4*)fB, nullptr);
    mm_kernel<64, 128, false, true, false><<<(NN + 31) / 32, 256, 0, stream>>>(
        fB, Wd2, bd2, dinv, (float4*)recon, nullptr);
}

// Round 10
// 237.247 us; speedup vs baseline: 1.1038x; 1.1038x over previous
//
#include <hip/hip_runtime.h>
#include <hip/hip_fp16.h>

#define NN 100000
#define NE 1600000
#define NB 782            // dst buckets of 128 nodes: ceil(NN/128)
#define EPB 2048          // edges per block in bucket phases
#define NBLK_A 782        // ceil(NE/EPB)
#define SCNT (NB * NBLK_A)             // 611524 (divisible by 4)
#define SC_NB ((SCNT + 1023) / 1024)   // 598
#define CAP 4096          // bucket capacity for LDS staging (mean 2046, sd ~45)

// ---------------- CSR build: atomic-light bucketing ----------------

__global__ void bhistA_kernel(const int* __restrict__ dst, int* __restrict__ histT) {
    __shared__ int hist[NB];
    int t = threadIdx.x, b = blockIdx.x;
    for (int i = t; i < NB; i += 256) hist[i] = 0;
    __syncthreads();
    int e0 = b * EPB + t * 4;
#pragma unroll
    for (int half = 0; half < 2; ++half) {
        int e = e0 + half * 1024;
        if (e < NE) {
            int4 d4 = *(const int4*)(dst + e);
            atomicAdd(&hist[d4.x >> 7], 1);
            atomicAdd(&hist[d4.y >> 7], 1);
            atomicAdd(&hist[d4.z >> 7], 1);
            atomicAdd(&hist[d4.w >> 7], 1);
        }
    }
    __syncthreads();
    for (int i = t; i < NB; i += 256) histT[i * NBLK_A + b] = hist[i];
}

__global__ void scan1g_kernel(const int* __restrict__ in, int* __restrict__ out,
                              int* __restrict__ blkSum) {
    __shared__ int ts[256];
    int t = threadIdx.x, b = blockIdx.x;
    int base = b * 1024 + t * 4;
    int4 c = {0, 0, 0, 0};
    if (base < SCNT) c = *(const int4*)(in + base);
    int s = c.x + c.y + c.z + c.w;
    ts[t] = s;
    __syncthreads();
    for (int ofs = 1; ofs < 256; ofs <<= 1) {
        int v = (t >= ofs) ? ts[t - ofs] : 0;
        __syncthreads();
        ts[t] += v;
        __syncthreads();
    }
    if (t == 255) blkSum[b] = ts[255];
    int ex = ts[t] - s;
    if (base < SCNT) {
        int4 p;
        p.x = ex; p.y = ex + c.x; p.z = p.y + c.y; p.w = p.z + c.z;
        *(int4*)(out + base) = p;
    }
}

__global__ void scan2g_kernel(int* __restrict__ blkSum) {  // SC_NB <= 1024
    __shared__ int ts[1024];
    int t = threadIdx.x;
    int v = (t < SC_NB) ? blkSum[t] : 0;
    ts[t] = v;
    __syncthreads();
    for (int ofs = 1; ofs < 1024; ofs <<= 1) {
        int u = (t >= ofs) ? ts[t - ofs] : 0;
        __syncthreads();
        ts[t] += u;
        __syncthreads();
    }
    if (t < SC_NB) blkSum[t] = ts[t] - v;
}

// Scatter packed (src | local_dst<<20); cursors = partial scan + folded block offset.
__global__ void bscatB_kernel(const int* __restrict__ src, const int* __restrict__ dst,
                              const int* __restrict__ scanT, const int* __restrict__ blkSum,
                              int* __restrict__ ebuf) {
    __shared__ int cur[NB];
    int t = threadIdx.x, b = blockIdx.x;
    for (int i = t; i < NB; i += 256) {
        int idx = i * NBLK_A + b;
        cur[i] = scanT[idx] + blkSum[idx >> 10];
    }
    __syncthreads();
    int e0 = b * EPB + t * 4;
#pragma unroll
    for (int half = 0; half < 2; ++half) {
        int e = e0 + half * 1024;
        if (e < NE) {
            int4 d4 = *(const int4*)(dst + e);
            int4 s4 = *(const int4*)(src + e);
            int p0 = atomicAdd(&cur[d4.x >> 7], 1);
            ebuf[p0] = s4.x | ((d4.x & 127) << 20);
            int p1 = atomicAdd(&cur[d4.y >> 7], 1);
            ebuf[p1] = s4.y | ((d4.y & 127) << 20);
            int p2 = atomicAdd(&cur[d4.z >> 7], 1);
            ebuf[p2] = s4.z | ((d4.z & 127) << 20);
            int p3 = atomicAdd(&cur[d4.w >> 7], 1);
            ebuf[p3] = s4.w | ((d4.w & 127) << 20);
        }
    }
}

// ---------------- helpers ----------------

__device__ inline ushort4 f4_to_h4(float4 v) {
    ushort4 o;
    o.x = __half_as_ushort(__float2half(v.x));
    o.y = __half_as_ushort(__float2half(v.y));
    o.z = __half_as_ushort(__float2half(v.z));
    o.w = __half_as_ushort(__float2half(v.w));
    return o;
}

// Per-bucket CSR finalize + fused quant of emb: row_ptr, col, dinv, qA=fp16(dinv*emb).
__global__ void csrC_kernel(const int* __restrict__ ebuf, const int* __restrict__ scanT,
                            const int* __restrict__ blkSum,
                            int* __restrict__ row_ptr, int* __restrict__ col,
                            float* __restrict__ dinv,
                            const float4* __restrict__ emb, ushort4* __restrict__ qA) {
    __shared__ int es[CAP];
    __shared__ int hist[128];
    __shared__ int ts[128];
    __shared__ int cur[128];
    __shared__ float dl[128];
    int t = threadIdx.x, b = blockIdx.x;
    int i0 = b * NBLK_A;
    int base = scanT[i0] + blkSum[i0 >> 10];
    int end;
    if (b + 1 < NB) {
        int i1 = (b + 1) * NBLK_A;
        end = scanT[i1] + blkSum[i1 >> 10];
    } else {
        end = NE;
    }
    int cnt = end - base;
    if (t < 128) hist[t] = 0;
    __syncthreads();
    for (int i = t; i < cnt; i += 256) {
        int e = ebuf[base + i];
        if (i < CAP) es[i] = e;
        atomicAdd(&hist[e >> 20], 1);
    }
    __syncthreads();
    if (t < 128) ts[t] = hist[t];
    __syncthreads();
    for (int ofs = 1; ofs < 128; ofs <<= 1) {
        int v = 0;
        if (t < 128 && t >= ofs) v = ts[t - ofs];
        __syncthreads();
        if (t < 128) ts[t] += v;
        __syncthreads();
    }
    if (t < 128) {
        int ex = ts[t] - hist[t];
        cur[t] = ex;
        float dv = rsqrtf((float)hist[t] + 1.0f);
        dl[t] = dv;
        int g = b * 128 + t;
        if (g < NN) {
            row_ptr[g] = base + ex;
            dinv[g] = dv;
        }
    }
    if (b == 0 && t == 0) row_ptr[NN] = NE;
    __syncthreads();
    for (int i = t; i < cnt; i += 256) {
        int e = (i < CAP) ? es[i] : ebuf[base + i];
        int r = atomicAdd(&cur[e >> 20], 1);  // LDS atomic
        col[base + r] = e & 0xFFFFF;
    }
    // fused quant: qA[g,:] = fp16(dinv[g] * emb[g,:])   (EMB=32 ch -> 8 float4/node)
    for (int i = t; i < 128 * 8; i += 256) {
        int ln = i >> 3;
        int g = b * 128 + ln;
        if (g < NN) {
            float4 v = emb[(size_t)g * 8 + (i & 7)];
            float d = dl[ln];
            v.x *= d; v.y *= d; v.z *= d; v.w *= d;
            qA[(size_t)g * 8 + (i & 7)] = f4_to_h4(v);
        }
    }
}

// ---------------- aggregation core (fp16 gather, f32 accum, int4 col loads) ----------------

__device__ inline void acc8(float* a, uint4 u) {
    const __half2* hp = (const __half2*)&u;
#pragma unroll
    for (int q = 0; q < 4; ++q) {
        float2 f = __half22float2(hp[q]);
        a[2 * q]     += f.x;
        a[2 * q + 1] += f.y;
    }
}

// Accumulate node's in-neighbors (+self) into a[8] for channel-group cg (TPN groups/row).
template<int TPN>
__device__ inline void agg_node(float* a, const uint4* __restrict__ h,
                                const int* __restrict__ col, int node, int beg, int end, int cg) {
    acc8(a, h[(size_t)node * TPN + cg]);  // self-loop term
    int j = beg;
    for (; j < end && (j & 3); ++j) acc8(a, h[(size_t)col[j] * TPN + cg]);
    for (; j + 8 <= end; j += 8) {
        int4 c0 = *(const int4*)(col + j);
        int4 c1 = *(const int4*)(col + j + 4);
        uint4 u0 = h[(size_t)c0.x * TPN + cg];
        uint4 u1 = h[(size_t)c0.y * TPN + cg];
        uint4 u2 = h[(size_t)c0.z * TPN + cg];
        uint4 u3 = h[(size_t)c0.w * TPN + cg];
        uint4 u4 = h[(size_t)c1.x * TPN + cg];
        uint4 u5 = h[(size_t)c1.y * TPN + cg];
        uint4 u6 = h[(size_t)c1.z * TPN + cg];
        uint4 u7 = h[(size_t)c1.w * TPN + cg];
        acc8(a, u0); acc8(a, u1); acc8(a, u2); acc8(a, u3);
        acc8(a, u4); acc8(a, u5); acc8(a, u6); acc8(a, u7);
    }
    for (; j + 4 <= end; j += 4) {
        int4 c0 = *(const int4*)(col + j);
        uint4 u0 = h[(size_t)c0.x * TPN + cg];
        uint4 u1 = h[(size_t)c0.y * TPN + cg];
        uint4 u2 = h[(size_t)c0.z * TPN + cg];
        uint4 u3 = h[(size_t)c0.w * TPN + cg];
        acc8(a, u0); acc8(a, u1); acc8(a, u2); acc8(a, u3);
    }
    for (; j < end; ++j) acc8(a, h[(size_t)col[j] * TPN + cg]);
}

// Standalone agg (layer 2): r = relu(dinv*s + b) -> out (f32) and qout (fp16*dinv).
template<int C, bool BIASRELU, bool WRITE_Q>
__global__ void agg_kernel(const uint4* __restrict__ h, const int* __restrict__ row_ptr,
                           const int* __restrict__ col, const float* __restrict__ dinv,
                           const float* __restrict__ b, float4* __restrict__ out,
                           uint4* __restrict__ qout) {
    constexpr int TPN = C / 8;
    int gid = blockIdx.x * blockDim.x + threadIdx.x;
    int node = gid / TPN;
    int cg = gid % TPN;
    if (node >= NN) return;
    float a[8] = {0, 0, 0, 0, 0, 0, 0, 0};
    agg_node<TPN>(a, h, col, node, row_ptr[node], row_ptr[node + 1], cg);
    float d = dinv[node];
    float r[8];
    if (BIASRELU) {
        const float* bp = b + cg * 8;
#pragma unroll
        for (int q = 0; q < 8; ++q) r[q] = fmaxf(fmaf(d, a[q], bp[q]), 0.f);
    } else {
#pragma unroll
        for (int q = 0; q < 8; ++q) r[q] = d * a[q];
    }
    float4* op = out + (size_t)node * (C / 4) + cg * 2;
    op[0] = make_float4(r[0], r[1], r[2], r[3]);
    op[1] = make_float4(r[4], r[5], r[6], r[7]);
    if (WRITE_Q) {
        uint4 qv;
        __half2* qp = (__half2*)&qv;
#pragma unroll
        for (int q = 0; q < 4; ++q)
            qp[q] = __float22half2_rn(make_float2(r[2 * q] * d, r[2 * q + 1] * d));
        qout[(size_t)node * TPN + cg] = qv;
    }
}

// ---------------- register-tiled matmul (standalone, layer 2) ----------------
template<int IN, int OUT, bool RELU, bool HASBIAS, bool QUANT>
__global__ void mm_kernel(const float* __restrict__ x, const float* __restrict__ W,
                          const float* __restrict__ bias, const float* __restrict__ dinv,
                          float4* __restrict__ out, ushort4* __restrict__ qout) {
    constexpr int CG   = OUT / 4;
    constexpr int RG   = 256 / CG;
    constexpr int ROWS = RG * 4;
    constexpr int P    = IN + 4;
    __shared__ float4 Ws[IN * CG];
    __shared__ float  xs[ROWS * P];

    int tid = threadIdx.x;
    const float4* W4 = (const float4*)W;
    for (int i = tid; i < IN * CG; i += 256) Ws[i] = W4[i];

    int n0 = blockIdx.x * ROWS;
    for (int i = tid; i < ROWS * IN; i += 256) {
        int r = i / IN, c = i & (IN - 1);
        size_t g = (size_t)n0 * IN + i;
        if (g < (size_t)NN * IN) xs[r * P + c] = x[g];
    }
    __syncthreads();

    int cg = tid % CG;
    int rg = tid / CG;

    float4 acc[4] = {{0,0,0,0},{0,0,0,0},{0,0,0,0},{0,0,0,0}};
#pragma unroll 2
    for (int k = 0; k < IN; k += 4) {
        float4 w0 = Ws[(k + 0) * CG + cg];
        float4 w1 = Ws[(k + 1) * CG + cg];
        float4 w2 = Ws[(k + 2) * CG + cg];
        float4 w3 = Ws[(k + 3) * CG + cg];
#pragma unroll
        for (int i = 0; i < 4; ++i) {
            float4 xq = *(const float4*)&xs[(i * RG + rg) * P + k];
            acc[i].x = fmaf(xq.x, w0.x, acc[i].x);
            acc[i].y = fmaf(xq.x, w0.y, acc[i].y);
            acc[i].z = fmaf(xq.x, w0.z, acc[i].z);
            acc[i].w = fmaf(xq.x, w0.w, acc[i].w);
            acc[i].x = fmaf(xq.y, w1.x, acc[i].x);
            acc[i].y = fmaf(xq.y, w1.y, acc[i].y);
            acc[i].z = fmaf(xq.y, w1.z, acc[i].z);
            acc[i].w = fmaf(xq.y, w1.w, acc[i].w);
            acc[i].x = fmaf(xq.z, w2.x, acc[i].x);
            acc[i].y = fmaf(xq.z, w2.y, acc[i].y);
            acc[i].z = fmaf(xq.z, w2.z, acc[i].z);
            acc[i].w = fmaf(xq.z, w2.w, acc[i].w);
            acc[i].x = fmaf(xq.w, w3.x, acc[i].x);
            acc[i].y = fmaf(xq.w, w3.y, acc[i].y);
            acc[i].z = fmaf(xq.w, w3.z, acc[i].z);
            acc[i].w = fmaf(xq.w, w3.w, acc[i].w);
        }
    }

    float4 bb = {0, 0, 0, 0};
    if (HASBIAS) bb = ((const float4*)bias)[cg];
#pragma unroll
    for (int i = 0; i < 4; ++i) {
        int node = n0 + i * RG + rg;
        if (node >= NN) continue;
        float4 r = acc[i];
        if (HASBIAS) { r.x += bb.x; r.y += bb.y; r.z += bb.z; r.w += bb.w; }
        if (RELU) {
            r.x = fmaxf(r.x, 0.f); r.y = fmaxf(r.y, 0.f);
            r.z = fmaxf(r.z, 0.f); r.w = fmaxf(r.w, 0.f);
        }
        if (QUANT) {
            float d = dinv[node];
            r.x *= d; r.y *= d; r.z *= d; r.w *= d;
            qout[(size_t)node * CG + cg] = f4_to_h4(r);
        } else {
            out[(size_t)node * CG + cg] = r;
        }
    }
}

// ---------------- FUSED agg + matmul (agg-first layers 1, 3, 4) ----------------
// Agg phase: IN/8 threads per node aggregate fp16 h into f32, scaled by dinv,
// written straight into the mm's LDS x-tile. Then register-tiled matmul.
template<int IN, int OUT, bool RELU, bool HASBIAS, bool QUANT>
__global__ void aggmm_kernel(const uint4* __restrict__ h, const int* __restrict__ row_ptr,
                             const int* __restrict__ col, const float* __restrict__ dinv,
                             const float* __restrict__ W, const float* __restrict__ bias,
                             float4* __restrict__ out, ushort4* __restrict__ qout) {
    constexpr int CG    = OUT / 4;     // 16 or 32
    constexpr int RG    = 256 / CG;    // 16 or 8
    constexpr int ROWS  = RG * 4;      // 64 or 32
    constexpr int P     = IN + 4;
    constexpr int TPN_A = IN / 8;      // agg threads per node: 4 or 8
    static_assert(ROWS * TPN_A == 256, "agg/mm decomposition mismatch");
    __shared__ float4 Ws[IN * CG];
    __shared__ float  xs[ROWS * P];

    int tid = threadIdx.x;
    const float4* W4 = (const float4*)W;
    for (int i = tid; i < IN * CG; i += 256) Ws[i] = W4[i];

    int n0 = blockIdx.x * ROWS;

    // ---- agg phase: fill xs[ln][cg*8 .. cg*8+8] ----
    {
        int ln = tid / TPN_A;
        int cg = tid % TPN_A;
        int node = n0 + ln;
        float a[8] = {0, 0, 0, 0, 0, 0, 0, 0};
        if (node < NN) {
            agg_node<TPN_A>(a, h, col, node, row_ptr[node], row_ptr[node + 1], cg);
            float d = dinv[node];
#pragma unroll
            for (int q = 0; q < 8; ++q) a[q] *= d;
        }
        float* xp = &xs[ln * P + cg * 8];
        *(float4*)xp       = make_float4(a[0], a[1], a[2], a[3]);
        *(float4*)(xp + 4) = make_float4(a[4], a[5], a[6], a[7]);
    }
    __syncthreads();

    // ---- mm phase ----
    int cg = tid % CG;
    int rg = tid / CG;

    float4 acc[4] = {{0,0,0,0},{0,0,0,0},{0,0,0,0},{0,0,0,0}};
#pragma unroll 2
    for (int k = 0; k < IN; k += 4) {
        float4 w0 = Ws[(k + 0) * CG + cg];
        float4 w1 = Ws[(k + 1) * CG + cg];
        float4 w2 = Ws[(k + 2) * CG + cg];
        float4 w3 = Ws[(k + 3) * CG + cg];
#pragma unroll
        for (int i = 0; i < 4; ++i) {
            float4 xq = *(const float4*)&xs[(i * RG + rg) * P + k];
            acc[i].x = fmaf(xq.x, w0.x, acc[i].x);
            acc[i].y = fmaf(xq.x, w0.y, acc[i].y);
            acc[i].z = fmaf(xq.x, w0.z, acc[i].z);
            acc[i].w = fmaf(xq.x, w0.w, acc[i].w);
            acc[i].x = fmaf(xq.y, w1.x, acc[i].x);
            acc[i].y = fmaf(xq.y, w1.y, acc[i].y);
            acc[i].z = fmaf(xq.y, w1.z, acc[i].z);
            acc[i].w = fmaf(xq.y, w1.w, acc[i].w);
            acc[i].x = fmaf(xq.z, w2.x, acc[i].x);
            acc[i].y = fmaf(xq.z, w2.y, acc[i].y);
            acc[i].z = fmaf(xq.z, w2.z, acc[i].z);
            acc[i].w = fmaf(xq.z, w2.w, acc[i].w);
            acc[i].x = fmaf(xq.w, w3.x, acc[i].x);
            acc[i].y = fmaf(xq.w, w3.y, acc[i].y);
            acc[i].z = fmaf(xq.w, w3.z, acc[i].z);
            acc[i].w = fmaf(xq.w, w3.w, acc[i].w);
        }
    }

    float4 bb = {0, 0, 0, 0};
    if (HASBIAS) bb = ((const float4*)bias)[cg];
#pragma unroll
    for (int i = 0; i < 4; ++i) {
        int node = n0 + i * RG + rg;
        if (node >= NN) continue;
        float4 r = acc[i];
        if (HASBIAS) { r.x += bb.x; r.y += bb.y; r.z += bb.z; r.w += bb.w; }
        if (RELU) {
            r.x = fmaxf(r.x, 0.f); r.y = fmaxf(r.y, 0.f);
            r.z = fmaxf(r.z, 0.f); r.w = fmaxf(r.w, 0.f);
        }
        if (QUANT) {
            float d = dinv[node];
            r.x *= d; r.y *= d; r.z *= d; r.w *= d;
            qout[(size_t)node * CG + cg] = f4_to_h4(r);
        } else {
            out[(size_t)node * CG + cg] = r;
        }
    }
}

// ---------------- launch ----------------

extern "C" void kernel_launch(void* const* d_in, const int* in_sizes, int n_in,
                              void* d_out, int out_size, void* d_ws, size_t ws_size,
                              hipStream_t stream) {
    const int* ei = (const int*)d_in[0];
    const int* src = ei;
    const int* dst = ei + NE;
    const float* emb = (const float*)d_in[1];
    const float* We1 = (const float*)d_in[2]; const float* be1 = (const float*)d_in[3];
    const float* We2 = (const float*)d_in[4]; const float* be2 = (const float*)d_in[5];
    const float* Wd1 = (const float*)d_in[6]; const float* bd1 = (const float*)d_in[7];
    const float* Wd2 = (const float*)d_in[8]; const float* bd2 = (const float*)d_in[9];

    float* outp  = (float*)d_out;
    float* recon = outp;                      // [NN*128]
    float* z     = outp + (size_t)NN * 128;   // [NN*32]

    char* ws = (char*)d_ws;
    size_t off = 0;
    auto alloc = [&](size_t bytes) {
        void* p = ws + off;
        off += (bytes + 255) & ~(size_t)255;
        return p;
    };
    int*     row_ptr = (int*)    alloc((size_t)(NN + 1) * 4);
    int*     col     = (int*)    alloc((size_t)NE * 4);
    float*   dinv    = (float*)  alloc((size_t)NN * 4);
    int*     histT   = (int*)    alloc((size_t)SCNT * 4);
    int*     scanT   = (int*)    alloc((size_t)SCNT * 4);
    int*     blkSum  = (int*)    alloc((size_t)SC_NB * 4);
    int*     ebuf    = (int*)    alloc((size_t)NE * 4);
    ushort4* qA      = (ushort4*)alloc((size_t)NN * 64 * 2);
    ushort4* qB      = (ushort4*)alloc((size_t)NN * 64 * 2);
    float*   fB      = (float*)  alloc((size_t)NN * 64 * 4);
    (void)ws_size; (void)in_sizes; (void)n_in; (void)out_size;

    // --- CSR build (bucketed, no global atomics) + fused emb quant ---
    bhistA_kernel<<<NBLK_A, 256, 0, stream>>>(dst, histT);
    scan1g_kernel<<<SC_NB, 256, 0, stream>>>(histT, scanT, blkSum);
    scan2g_kernel<<<1, 1024, 0, stream>>>(blkSum);
    bscatB_kernel<<<NBLK_A, 256, 0, stream>>>(src, dst, scanT, blkSum, ebuf);
    csrC_kernel<<<NB, 256, 0, stream>>>(ebuf, scanT, blkSum, row_ptr, col, dinv,
                                        (const float4*)emb, qA);

    // --- layer 1 (fused agg+mm): x1 = relu((dinv*(q1+Σ))@We1 + be1) -> fB ---
    aggmm_kernel<32, 64, true, true, false><<<(NN + 63) / 64, 256, 0, stream>>>(
        (const uint4*)qA, row_ptr, col, dinv, We1, be1, (float4*)fB, nullptr);

    // --- layer 2 (transform-first): h2 = fp16(dinv*(x1@We2)); z = relu(dinv*(h2+Σ)+be2); q3 = fp16(dinv*z) ---
    mm_kernel<64, 32, false, false, true><<<(NN + 127) / 128, 256, 0, stream>>>(
        fB, We2, nullptr, dinv, nullptr, qB);
    agg_kernel<32, true, true><<<(NN * 4 + 255) / 256, 256, 0, stream>>>(
        (const uint4*)qB, row_ptr, col, dinv, be2, (float4*)z, (uint4*)qA);

    // --- layer 3 (fused agg+mm): q4 = fp16(dinv*relu((dinv*(q3+Σ))@Wd1 + bd1)) ---
    aggmm_kernel<32, 64, true, true, true><<<(NN + 63) / 64, 256, 0, stream>>>(
        (const uint4*)qA, row_ptr, col, dinv, Wd1, bd1, nullptr, (ushort4*)qB);

    // --- layer 4 (fused agg+mm): recon = (dinv*(q4+Σ))@Wd2 + bd2 ---
    aggmm_kernel<64, 128, false, true, false><<<(NN + 31) / 32, 256, 0, stream>>>(
        (const uint4*)qB, row_ptr, col, dinv, Wd2, bd2, (float4*)recon, nullptr);
}

// Round 11
// 233.983 us; speedup vs baseline: 1.1192x; 1.0140x over previous
//
#include <hip/hip_runtime.h>
#include <hip/hip_fp16.h>

#define NN 100000
#define NE 1600000
#define NB 782            // dst buckets of 128 nodes: ceil(NN/128)
#define EPB 2048          // edges per block in bucket phases
#define NBLK_A 782        // ceil(NE/EPB)
#define SCNT (NB * NBLK_A)             // 611524 (divisible by 4)
#define SC_NB ((SCNT + 1023) / 1024)   // 598
#define CAP 4096          // bucket capacity for LDS staging (mean 2046, sd ~45)

// ---------------- CSR build: atomic-light bucketing ----------------

__global__ void bhistA_kernel(const int* __restrict__ dst, int* __restrict__ histT) {
    __shared__ int hist[NB];
    int t = threadIdx.x, b = blockIdx.x;
    for (int i = t; i < NB; i += 256) hist[i] = 0;
    __syncthreads();
    int e0 = b * EPB + t * 4;
#pragma unroll
    for (int half = 0; half < 2; ++half) {
        int e = e0 + half * 1024;
        if (e < NE) {
            int4 d4 = *(const int4*)(dst + e);
            atomicAdd(&hist[d4.x >> 7], 1);
            atomicAdd(&hist[d4.y >> 7], 1);
            atomicAdd(&hist[d4.z >> 7], 1);
            atomicAdd(&hist[d4.w >> 7], 1);
        }
    }
    __syncthreads();
    for (int i = t; i < NB; i += 256) histT[i * NBLK_A + b] = hist[i];
}

__global__ void scan1g_kernel(const int* __restrict__ in, int* __restrict__ out,
                              int* __restrict__ blkSum) {
    __shared__ int ts[256];
    int t = threadIdx.x, b = blockIdx.x;
    int base = b * 1024 + t * 4;
    int4 c = {0, 0, 0, 0};
    if (base < SCNT) c = *(const int4*)(in + base);
    int s = c.x + c.y + c.z + c.w;
    ts[t] = s;
    __syncthreads();
    for (int ofs = 1; ofs < 256; ofs <<= 1) {
        int v = (t >= ofs) ? ts[t - ofs] : 0;
        __syncthreads();
        ts[t] += v;
        __syncthreads();
    }
    if (t == 255) blkSum[b] = ts[255];
    int ex = ts[t] - s;
    if (base < SCNT) {
        int4 p;
        p.x = ex; p.y = ex + c.x; p.z = p.y + c.y; p.w = p.z + c.z;
        *(int4*)(out + base) = p;
    }
}

__global__ void scan2g_kernel(int* __restrict__ blkSum) {  // SC_NB <= 1024
    __shared__ int ts[1024];
    int t = threadIdx.x;
    int v = (t < SC_NB) ? blkSum[t] : 0;
    ts[t] = v;
    __syncthreads();
    for (int ofs = 1; ofs < 1024; ofs <<= 1) {
        int u = (t >= ofs) ? ts[t - ofs] : 0;
        __syncthreads();
        ts[t] += u;
        __syncthreads();
    }
    if (t < SC_NB) blkSum[t] = ts[t] - v;
}

// Scatter packed (src | local_dst<<20); cursors = partial scan + folded block offset.
__global__ void bscatB_kernel(const int* __restrict__ src, const int* __restrict__ dst,
                              const int* __restrict__ scanT, const int* __restrict__ blkSum,
                              int* __restrict__ ebuf) {
    __shared__ int cur[NB];
    int t = threadIdx.x, b = blockIdx.x;
    for (int i = t; i < NB; i += 256) {
        int idx = i * NBLK_A + b;
        cur[i] = scanT[idx] + blkSum[idx >> 10];
    }
    __syncthreads();
    int e0 = b * EPB + t * 4;
#pragma unroll
    for (int half = 0; half < 2; ++half) {
        int e = e0 + half * 1024;
        if (e < NE) {
            int4 d4 = *(const int4*)(dst + e);
            int4 s4 = *(const int4*)(src + e);
            int p0 = atomicAdd(&cur[d4.x >> 7], 1);
            ebuf[p0] = s4.x | ((d4.x & 127) << 20);
            int p1 = atomicAdd(&cur[d4.y >> 7], 1);
            ebuf[p1] = s4.y | ((d4.y & 127) << 20);
            int p2 = atomicAdd(&cur[d4.z >> 7], 1);
            ebuf[p2] = s4.z | ((d4.z & 127) << 20);
            int p3 = atomicAdd(&cur[d4.w >> 7], 1);
            ebuf[p3] = s4.w | ((d4.w & 127) << 20);
        }
    }
}

// ---------------- helpers ----------------

__device__ inline ushort4 f4_to_h4(float4 v) {
    ushort4 o;
    o.x = __half_as_ushort(__float2half(v.x));
    o.y = __half_as_ushort(__float2half(v.y));
    o.z = __half_as_ushort(__float2half(v.z));
    o.w = __half_as_ushort(__float2half(v.w));
    return o;
}

// Per-bucket CSR finalize + fused quant of emb: row_ptr, col, dinv, qA=fp16(dinv*emb).
__global__ void csrC_kernel(const int* __restrict__ ebuf, const int* __restrict__ scanT,
                            const int* __restrict__ blkSum,
                            int* __restrict__ row_ptr, int* __restrict__ col,
                            float* __restrict__ dinv,
                            const float4* __restrict__ emb, ushort4* __restrict__ qA) {
    __shared__ int es[CAP];
    __shared__ int hist[128];
    __shared__ int ts[128];
    __shared__ int cur[128];
    __shared__ float dl[128];
    int t = threadIdx.x, b = blockIdx.x;
    int i0 = b * NBLK_A;
    int base = scanT[i0] + blkSum[i0 >> 10];
    int end;
    if (b + 1 < NB) {
        int i1 = (b + 1) * NBLK_A;
        end = scanT[i1] + blkSum[i1 >> 10];
    } else {
        end = NE;
    }
    int cnt = end - base;
    if (t < 128) hist[t] = 0;
    __syncthreads();
    for (int i = t; i < cnt; i += 256) {
        int e = ebuf[base + i];
        if (i < CAP) es[i] = e;
        atomicAdd(&hist[e >> 20], 1);
    }
    __syncthreads();
    if (t < 128) ts[t] = hist[t];
    __syncthreads();
    for (int ofs = 1; ofs < 128; ofs <<= 1) {
        int v = 0;
        if (t < 128 && t >= ofs) v = ts[t - ofs];
        __syncthreads();
        if (t < 128) ts[t] += v;
        __syncthreads();
    }
    if (t < 128) {
        int ex = ts[t] - hist[t];
        cur[t] = ex;
        float dv = rsqrtf((float)hist[t] + 1.0f);
        dl[t] = dv;
        int g = b * 128 + t;
        if (g < NN) {
            row_ptr[g] = base + ex;
            dinv[g] = dv;
        }
    }
    if (b == 0 && t == 0) row_ptr[NN] = NE;
    __syncthreads();
    for (int i = t; i < cnt; i += 256) {
        int e = (i < CAP) ? es[i] : ebuf[base + i];
        int r = atomicAdd(&cur[e >> 20], 1);  // LDS atomic
        col[base + r] = e & 0xFFFFF;
    }
    // fused quant: qA[g,:] = fp16(dinv[g] * emb[g,:])   (EMB=32 ch -> 8 float4/node)
    for (int i = t; i < 128 * 8; i += 256) {
        int ln = i >> 3;
        int g = b * 128 + ln;
        if (g < NN) {
            float4 v = emb[(size_t)g * 8 + (i & 7)];
            float d = dl[ln];
            v.x *= d; v.y *= d; v.z *= d; v.w *= d;
            qA[(size_t)g * 8 + (i & 7)] = f4_to_h4(v);
        }
    }
}

// ---------------- aggregation core (fp16 gather, f32 accum, int4 col loads) ----------------

__device__ inline void acc8(float* a, uint4 u) {
    const __half2* hp = (const __half2*)&u;
#pragma unroll
    for (int q = 0; q < 4; ++q) {
        float2 f = __half22float2(hp[q]);
        a[2 * q]     += f.x;
        a[2 * q + 1] += f.y;
    }
}

// Accumulate node's in-neighbors (+self) into a[8] for channel-group cg (TPN groups/row).
template<int TPN>
__device__ inline void agg_node(float* a, const uint4* __restrict__ h,
                                const int* __restrict__ col, int node, int beg, int end, int cg) {
    acc8(a, h[(size_t)node * TPN + cg]);  // self-loop term
    int j = beg;
    for (; j < end && (j & 3); ++j) acc8(a, h[(size_t)col[j] * TPN + cg]);
    for (; j + 8 <= end; j += 8) {
        int4 c0 = *(const int4*)(col + j);
        int4 c1 = *(const int4*)(col + j + 4);
        uint4 u0 = h[(size_t)c0.x * TPN + cg];
        uint4 u1 = h[(size_t)c0.y * TPN + cg];
        uint4 u2 = h[(size_t)c0.z * TPN + cg];
        uint4 u3 = h[(size_t)c0.w * TPN + cg];
        uint4 u4 = h[(size_t)c1.x * TPN + cg];
        uint4 u5 = h[(size_t)c1.y * TPN + cg];
        uint4 u6 = h[(size_t)c1.z * TPN + cg];
        uint4 u7 = h[(size_t)c1.w * TPN + cg];
        acc8(a, u0); acc8(a, u1); acc8(a, u2); acc8(a, u3);
        acc8(a, u4); acc8(a, u5); acc8(a, u6); acc8(a, u7);
    }
    for (; j + 4 <= end; j += 4) {
        int4 c0 = *(const int4*)(col + j);
        uint4 u0 = h[(size_t)c0.x * TPN + cg];
        uint4 u1 = h[(size_t)c0.y * TPN + cg];
        uint4 u2 = h[(size_t)c0.z * TPN + cg];
        uint4 u3 = h[(size_t)c0.w * TPN + cg];
        acc8(a, u0); acc8(a, u1); acc8(a, u2); acc8(a, u3);
    }
    for (; j < end; ++j) acc8(a, h[(size_t)col[j] * TPN + cg]);
}

// Standalone agg (layer 2): r = relu(dinv*s + b) -> out (f32) and qout (fp16*dinv).
template<int C, bool BIASRELU, bool WRITE_Q>
__global__ void agg_kernel(const uint4* __restrict__ h, const int* __restrict__ row_ptr,
                           const int* __restrict__ col, const float* __restrict__ dinv,
                           const float* __restrict__ b, float4* __restrict__ out,
                           uint4* __restrict__ qout) {
    constexpr int TPN = C / 8;
    int gid = blockIdx.x * blockDim.x + threadIdx.x;
    int node = gid / TPN;
    int cg = gid % TPN;
    if (node >= NN) return;
    float a[8] = {0, 0, 0, 0, 0, 0, 0, 0};
    agg_node<TPN>(a, h, col, node, row_ptr[node], row_ptr[node + 1], cg);
    float d = dinv[node];
    float r[8];
    if (BIASRELU) {
        const float* bp = b + cg * 8;
#pragma unroll
        for (int q = 0; q < 8; ++q) r[q] = fmaxf(fmaf(d, a[q], bp[q]), 0.f);
    } else {
#pragma unroll
        for (int q = 0; q < 8; ++q) r[q] = d * a[q];
    }
    float4* op = out + (size_t)node * (C / 4) + cg * 2;
    op[0] = make_float4(r[0], r[1], r[2], r[3]);
    op[1] = make_float4(r[4], r[5], r[6], r[7]);
    if (WRITE_Q) {
        uint4 qv;
        __half2* qp = (__half2*)&qv;
#pragma unroll
        for (int q = 0; q < 4; ++q)
            qp[q] = __float22half2_rn(make_float2(r[2 * q] * d, r[2 * q + 1] * d));
        qout[(size_t)node * TPN + cg] = qv;
    }
}

// ---------------- register-tiled matmul (standalone, layer 2) ----------------
template<int IN, int OUT, bool RELU, bool HASBIAS, bool QUANT>
__global__ void mm_kernel(const float* __restrict__ x, const float* __restrict__ W,
                          const float* __restrict__ bias, const float* __restrict__ dinv,
                          float4* __restrict__ out, ushort4* __restrict__ qout) {
    constexpr int CG   = OUT / 4;
    constexpr int RG   = 256 / CG;
    constexpr int ROWS = RG * 4;
    constexpr int P    = IN + 4;
    __shared__ float4 Ws[IN * CG];
    __shared__ float  xs[ROWS * P];

    int tid = threadIdx.x;
    const float4* W4 = (const float4*)W;
    for (int i = tid; i < IN * CG; i += 256) Ws[i] = W4[i];

    int n0 = blockIdx.x * ROWS;
    for (int i = tid; i < ROWS * IN; i += 256) {
        int r = i / IN, c = i & (IN - 1);
        size_t g = (size_t)n0 * IN + i;
        if (g < (size_t)NN * IN) xs[r * P + c] = x[g];
    }
    __syncthreads();

    int cg = tid % CG;
    int rg = tid / CG;

    float4 acc[4] = {{0,0,0,0},{0,0,0,0},{0,0,0,0},{0,0,0,0}};
#pragma unroll 2
    for (int k = 0; k < IN; k += 4) {
        float4 w0 = Ws[(k + 0) * CG + cg];
        float4 w1 = Ws[(k + 1) * CG + cg];
        float4 w2 = Ws[(k + 2) * CG + cg];
        float4 w3 = Ws[(k + 3) * CG + cg];
#pragma unroll
        for (int i = 0; i < 4; ++i) {
            float4 xq = *(const float4*)&xs[(i * RG + rg) * P + k];
            acc[i].x = fmaf(xq.x, w0.x, acc[i].x);
            acc[i].y = fmaf(xq.x, w0.y, acc[i].y);
            acc[i].z = fmaf(xq.x, w0.z, acc[i].z);
            acc[i].w = fmaf(xq.x, w0.w, acc[i].w);
            acc[i].x = fmaf(xq.y, w1.x, acc[i].x);
            acc[i].y = fmaf(xq.y, w1.y, acc[i].y);
            acc[i].z = fmaf(xq.y, w1.z, acc[i].z);
            acc[i].w = fmaf(xq.y, w1.w, acc[i].w);
            acc[i].x = fmaf(xq.z, w2.x, acc[i].x);
            acc[i].y = fmaf(xq.z, w2.y, acc[i].y);
            acc[i].z = fmaf(xq.z, w2.z, acc[i].z);
            acc[i].w = fmaf(xq.z, w2.w, acc[i].w);
            acc[i].x = fmaf(xq.w, w3.x, acc[i].x);
            acc[i].y = fmaf(xq.w, w3.y, acc[i].y);
            acc[i].z = fmaf(xq.w, w3.z, acc[i].z);
            acc[i].w = fmaf(xq.w, w3.w, acc[i].w);
        }
    }

    float4 bb = {0, 0, 0, 0};
    if (HASBIAS) bb = ((const float4*)bias)[cg];
#pragma unroll
    for (int i = 0; i < 4; ++i) {
        int node = n0 + i * RG + rg;
        if (node >= NN) continue;
        float4 r = acc[i];
        if (HASBIAS) { r.x += bb.x; r.y += bb.y; r.z += bb.z; r.w += bb.w; }
        if (RELU) {
            r.x = fmaxf(r.x, 0.f); r.y = fmaxf(r.y, 0.f);
            r.z = fmaxf(r.z, 0.f); r.w = fmaxf(r.w, 0.f);
        }
        if (QUANT) {
            float d = dinv[node];
            r.x *= d; r.y *= d; r.z *= d; r.w *= d;
            qout[(size_t)node * CG + cg] = f4_to_h4(r);
        } else {
            out[(size_t)node * CG + cg] = r;
        }
    }
}

// ---------------- FUSED agg + matmul (agg-first layers 1, 3, 4) ----------------
// BS threads; agg phase: IN/8 threads per node aggregate fp16 h into f32,
// scaled by dinv, straight into the mm's LDS x-tile. Then register-tiled mm.
template<int IN, int OUT, int BS, bool RELU, bool HASBIAS, bool QUANT>
__global__ __launch_bounds__(BS) void aggmm_kernel(
        const uint4* __restrict__ h, const int* __restrict__ row_ptr,
        const int* __restrict__ col, const float* __restrict__ dinv,
        const float* __restrict__ W, const float* __restrict__ bias,
        float4* __restrict__ out, ushort4* __restrict__ qout) {
    constexpr int CG    = OUT / 4;
    constexpr int RG    = BS / CG;
    constexpr int ROWS  = RG * 4;
    constexpr int P     = IN + 4;
    constexpr int TPN_A = IN / 8;      // agg threads per node
    static_assert(ROWS * TPN_A == BS, "agg/mm decomposition mismatch");
    __shared__ float4 Ws[IN * CG];
    __shared__ float  xs[ROWS * P];

    int tid = threadIdx.x;
    const float4* W4 = (const float4*)W;
    for (int i = tid; i < IN * CG; i += BS) Ws[i] = W4[i];

    int n0 = blockIdx.x * ROWS;

    // ---- agg phase: fill xs[ln][cg*8 .. cg*8+8] ----
    {
        int ln = tid / TPN_A;
        int cg = tid % TPN_A;
        int node = n0 + ln;
        float a[8] = {0, 0, 0, 0, 0, 0, 0, 0};
        if (node < NN) {
            agg_node<TPN_A>(a, h, col, node, row_ptr[node], row_ptr[node + 1], cg);
            float d = dinv[node];
#pragma unroll
            for (int q = 0; q < 8; ++q) a[q] *= d;
        }
        float* xp = &xs[ln * P + cg * 8];
        *(float4*)xp       = make_float4(a[0], a[1], a[2], a[3]);
        *(float4*)(xp + 4) = make_float4(a[4], a[5], a[6], a[7]);
    }
    __syncthreads();

    // ---- mm phase ----
    int cg = tid % CG;
    int rg = tid / CG;

    float4 acc[4] = {{0,0,0,0},{0,0,0,0},{0,0,0,0},{0,0,0,0}};
#pragma unroll 2
    for (int k = 0; k < IN; k += 4) {
        float4 w0 = Ws[(k + 0) * CG + cg];
        float4 w1 = Ws[(k + 1) * CG + cg];
        float4 w2 = Ws[(k + 2) * CG + cg];
        float4 w3 = Ws[(k + 3) * CG + cg];
#pragma unroll
        for (int i = 0; i < 4; ++i) {
            float4 xq = *(const float4*)&xs[(i * RG + rg) * P + k];
            acc[i].x = fmaf(xq.x, w0.x, acc[i].x);
            acc[i].y = fmaf(xq.x, w0.y, acc[i].y);
            acc[i].z = fmaf(xq.x, w0.z, acc[i].z);
            acc[i].w = fmaf(xq.x, w0.w, acc[i].w);
            acc[i].x = fmaf(xq.y, w1.x, acc[i].x);
            acc[i].y = fmaf(xq.y, w1.y, acc[i].y);
            acc[i].z = fmaf(xq.y, w1.z, acc[i].z);
            acc[i].w = fmaf(xq.y, w1.w, acc[i].w);
            acc[i].x = fmaf(xq.z, w2.x, acc[i].x);
            acc[i].y = fmaf(xq.z, w2.y, acc[i].y);
            acc[i].z = fmaf(xq.z, w2.z, acc[i].z);
            acc[i].w = fmaf(xq.z, w2.w, acc[i].w);
            acc[i].x = fmaf(xq.w, w3.x, acc[i].x);
            acc[i].y = fmaf(xq.w, w3.y, acc[i].y);
            acc[i].z = fmaf(xq.w, w3.z, acc[i].z);
            acc[i].w = fmaf(xq.w, w3.w, acc[i].w);
        }
    }

    float4 bb = {0, 0, 0, 0};
    if (HASBIAS) bb = ((const float4*)bias)[cg];
#pragma unroll
    for (int i = 0; i < 4; ++i) {
        int node = n0 + i * RG + rg;
        if (node >= NN) continue;
        float4 r = acc[i];
        if (HASBIAS) { r.x += bb.x; r.y += bb.y; r.z += bb.z; r.w += bb.w; }
        if (RELU) {
            r.x = fmaxf(r.x, 0.f); r.y = fmaxf(r.y, 0.f);
            r.z = fmaxf(r.z, 0.f); r.w = fmaxf(r.w, 0.f);
        }
        if (QUANT) {
            float d = dinv[node];
            r.x *= d; r.y *= d; r.z *= d; r.w *= d;
            qout[(size_t)node * CG + cg] = f4_to_h4(r);
        } else {
            out[(size_t)node * CG + cg] = r;
        }
    }
}

// ---------------- launch ----------------

extern "C" void kernel_launch(void* const* d_in, const int* in_sizes, int n_in,
                              void* d_out, int out_size, void* d_ws, size_t ws_size,
                              hipStream_t stream) {
    const int* ei = (const int*)d_in[0];
    const int* src = ei;
    const int* dst = ei + NE;
    const float* emb = (const float*)d_in[1];
    const float* We1 = (const float*)d_in[2]; const float* be1 = (const float*)d_in[3];
    const float* We2 = (const float*)d_in[4]; const float* be2 = (const float*)d_in[5];
    const float* Wd1 = (const float*)d_in[6]; const float* bd1 = (const float*)d_in[7];
    const float* Wd2 = (const float*)d_in[8]; const float* bd2 = (const float*)d_in[9];

    float* outp  = (float*)d_out;
    float* recon = outp;                      // [NN*128]
    float* z     = outp + (size_t)NN * 128;   // [NN*32]

    char* ws = (char*)d_ws;
    size_t off = 0;
    auto alloc = [&](size_t bytes) {
        void* p = ws + off;
        off += (bytes + 255) & ~(size_t)255;
        return p;
    };
    int*     row_ptr = (int*)    alloc((size_t)(NN + 1) * 4);
    int*     col     = (int*)    alloc((size_t)NE * 4);
    float*   dinv    = (float*)  alloc((size_t)NN * 4);
    int*     histT   = (int*)    alloc((size_t)SCNT * 4);
    int*     scanT   = (int*)    alloc((size_t)SCNT * 4);
    int*     blkSum  = (int*)    alloc((size_t)SC_NB * 4);
    int*     ebuf    = (int*)    alloc((size_t)NE * 4);
    ushort4* qA      = (ushort4*)alloc((size_t)NN * 64 * 2);
    ushort4* qB      = (ushort4*)alloc((size_t)NN * 64 * 2);
    float*   fB      = (float*)  alloc((size_t)NN * 64 * 4);
    (void)ws_size; (void)in_sizes; (void)n_in; (void)out_size;

    // --- CSR build (bucketed, no global atomics) + fused emb quant ---
    bhistA_kernel<<<NBLK_A, 256, 0, stream>>>(dst, histT);
    scan1g_kernel<<<SC_NB, 256, 0, stream>>>(histT, scanT, blkSum);
    scan2g_kernel<<<1, 1024, 0, stream>>>(blkSum);
    bscatB_kernel<<<NBLK_A, 256, 0, stream>>>(src, dst, scanT, blkSum, ebuf);
    csrC_kernel<<<NB, 256, 0, stream>>>(ebuf, scanT, blkSum, row_ptr, col, dinv,
                                        (const float4*)emb, qA);

    // --- layer 1 (fused agg+mm, 256 thr): x1 = relu((dinv*(q1+Σ))@We1 + be1) -> fB ---
    aggmm_kernel<32, 64, 256, true, true, false><<<(NN + 63) / 64, 256, 0, stream>>>(
        (const uint4*)qA, row_ptr, col, dinv, We1, be1, (float4*)fB, nullptr);

    // --- layer 2 (transform-first): h2 = fp16(dinv*(x1@We2)); z = relu(dinv*(h2+Σ)+be2); q3 = fp16(dinv*z) ---
    mm_kernel<64, 32, false, false, true><<<(NN + 127) / 128, 256, 0, stream>>>(
        fB, We2, nullptr, dinv, nullptr, qB);
    agg_kernel<32, true, true><<<(NN * 4 + 255) / 256, 256, 0, stream>>>(
        (const uint4*)qB, row_ptr, col, dinv, be2, (float4*)z, (uint4*)qA);

    // --- layer 3 (fused agg+mm, 256 thr): q4 = fp16(dinv*relu((dinv*(q3+Σ))@Wd1 + bd1)) ---
    aggmm_kernel<32, 64, 256, true, true, true><<<(NN + 63) / 64, 256, 0, stream>>>(
        (const uint4*)qA, row_ptr, col, dinv, Wd1, bd1, nullptr, (ushort4*)qB);

    // --- layer 4 (fused agg+mm, 512 thr; ROWS=64 -> 50KB LDS, 24 waves/CU): recon = (dinv*(q4+Σ))@Wd2 + bd2 ---
    aggmm_kernel<64, 128, 512, false, true, false><<<(NN + 63) / 64, 512, 0, stream>>>(
        (const uint4*)qB, row_ptr, col, dinv, Wd2, bd2, (float4*)recon, nullptr);
}

// Round 12
// 222.070 us; speedup vs baseline: 1.1793x; 1.0536x over previous
//
#include <hip/hip_runtime.h>
#include <hip/hip_fp16.h>

#define NN 100000
#define NE 1600000
#define NB 782            // dst buckets of 128 nodes: ceil(NN/128)
#define EPB 8192          // edges per block in bucket phases (42B avg segments)
#define NBLK_A 196        // ceil(NE/EPB)
#define SCNT (NB * NBLK_A)             // 153272 (divisible by 4)
#define SC_NB ((SCNT + 1023) / 1024)   // 150
#define CAP 4096          // bucket capacity for LDS staging (mean 2046, sd ~45)

// ---------------- CSR build: atomic-light bucketing ----------------

__global__ __launch_bounds__(1024) void bhistA_kernel(const int* __restrict__ dst,
                                                      int* __restrict__ histT) {
    __shared__ int hist[NB];
    int t = threadIdx.x, b = blockIdx.x;
    for (int i = t; i < NB; i += 1024) hist[i] = 0;
    __syncthreads();
    int e0 = b * EPB + t * 4;
#pragma unroll
    for (int rep = 0; rep < 2; ++rep) {
        int e = e0 + rep * 4096;
        if (e < NE) {   // NE%4==0 && e%4==0 -> e+3 in bounds
            int4 d4 = *(const int4*)(dst + e);
            atomicAdd(&hist[d4.x >> 7], 1);
            atomicAdd(&hist[d4.y >> 7], 1);
            atomicAdd(&hist[d4.z >> 7], 1);
            atomicAdd(&hist[d4.w >> 7], 1);
        }
    }
    __syncthreads();
    for (int i = t; i < NB; i += 1024) histT[i * NBLK_A + b] = hist[i];
}

__global__ void scan1g_kernel(const int* __restrict__ in, int* __restrict__ out,
                              int* __restrict__ blkSum) {
    __shared__ int ts[256];
    int t = threadIdx.x, b = blockIdx.x;
    int base = b * 1024 + t * 4;
    int4 c = {0, 0, 0, 0};
    if (base < SCNT) c = *(const int4*)(in + base);
    int s = c.x + c.y + c.z + c.w;
    ts[t] = s;
    __syncthreads();
    for (int ofs = 1; ofs < 256; ofs <<= 1) {
        int v = (t >= ofs) ? ts[t - ofs] : 0;
        __syncthreads();
        ts[t] += v;
        __syncthreads();
    }
    if (t == 255) blkSum[b] = ts[255];
    int ex = ts[t] - s;
    if (base < SCNT) {
        int4 p;
        p.x = ex; p.y = ex + c.x; p.z = p.y + c.y; p.w = p.z + c.z;
        *(int4*)(out + base) = p;
    }
}

__global__ void scan2g_kernel(int* __restrict__ blkSum) {  // SC_NB <= 256
    __shared__ int ts[256];
    int t = threadIdx.x;
    int v = (t < SC_NB) ? blkSum[t] : 0;
    ts[t] = v;
    __syncthreads();
    for (int ofs = 1; ofs < 256; ofs <<= 1) {
        int u = (t >= ofs) ? ts[t - ofs] : 0;
        __syncthreads();
        ts[t] += u;
        __syncthreads();
    }
    if (t < SC_NB) blkSum[t] = ts[t] - v;
}

// Scatter packed (src | local_dst<<20); cursors = partial scan + folded block offset.
__global__ __launch_bounds__(1024) void bscatB_kernel(
        const int* __restrict__ src, const int* __restrict__ dst,
        const int* __restrict__ scanT, const int* __restrict__ blkSum,
        int* __restrict__ ebuf) {
    __shared__ int cur[NB];
    int t = threadIdx.x, b = blockIdx.x;
    for (int i = t; i < NB; i += 1024) {
        int idx = i * NBLK_A + b;
        cur[i] = scanT[idx] + blkSum[idx >> 10];
    }
    __syncthreads();
    int e0 = b * EPB + t * 4;
#pragma unroll
    for (int rep = 0; rep < 2; ++rep) {
        int e = e0 + rep * 4096;
        if (e < NE) {
            int4 d4 = *(const int4*)(dst + e);
            int4 s4 = *(const int4*)(src + e);
            int p0 = atomicAdd(&cur[d4.x >> 7], 1);
            ebuf[p0] = s4.x | ((d4.x & 127) << 20);
            int p1 = atomicAdd(&cur[d4.y >> 7], 1);
            ebuf[p1] = s4.y | ((d4.y & 127) << 20);
            int p2 = atomicAdd(&cur[d4.z >> 7], 1);
            ebuf[p2] = s4.z | ((d4.z & 127) << 20);
            int p3 = atomicAdd(&cur[d4.w >> 7], 1);
            ebuf[p3] = s4.w | ((d4.w & 127) << 20);
        }
    }
}

// ---------------- helpers ----------------

__device__ inline ushort4 f4_to_h4(float4 v) {
    ushort4 o;
    o.x = __half_as_ushort(__float2half(v.x));
    o.y = __half_as_ushort(__float2half(v.y));
    o.z = __half_as_ushort(__float2half(v.z));
    o.w = __half_as_ushort(__float2half(v.w));
    return o;
}

// Per-bucket CSR finalize + fused quant of emb: row_ptr, col, dinv, qA=fp16(dinv*emb).
__global__ void csrC_kernel(const int* __restrict__ ebuf, const int* __restrict__ scanT,
                            const int* __restrict__ blkSum,
                            int* __restrict__ row_ptr, int* __restrict__ col,
                            float* __restrict__ dinv,
                            const float4* __restrict__ emb, ushort4* __restrict__ qA) {
    __shared__ int es[CAP];
    __shared__ int hist[128];
    __shared__ int ts[128];
    __shared__ int cur[128];
    __shared__ float dl[128];
    int t = threadIdx.x, b = blockIdx.x;
    int i0 = b * NBLK_A;
    int base = scanT[i0] + blkSum[i0 >> 10];
    int end;
    if (b + 1 < NB) {
        int i1 = (b + 1) * NBLK_A;
        end = scanT[i1] + blkSum[i1 >> 10];
    } else {
        end = NE;
    }
    int cnt = end - base;
    if (t < 128) hist[t] = 0;
    __syncthreads();
    for (int i = t; i < cnt; i += 256) {
        int e = ebuf[base + i];
        if (i < CAP) es[i] = e;
        atomicAdd(&hist[e >> 20], 1);
    }
    __syncthreads();
    if (t < 128) ts[t] = hist[t];
    __syncthreads();
    for (int ofs = 1; ofs < 128; ofs <<= 1) {
        int v = 0;
        if (t < 128 && t >= ofs) v = ts[t - ofs];
        __syncthreads();
        if (t < 128) ts[t] += v;
        __syncthreads();
    }
    if (t < 128) {
        int ex = ts[t] - hist[t];
        cur[t] = ex;
        float dv = rsqrtf((float)hist[t] + 1.0f);
        dl[t] = dv;
        int g = b * 128 + t;
        if (g < NN) {
            row_ptr[g] = base + ex;
            dinv[g] = dv;
        }
    }
    if (b == 0 && t == 0) row_ptr[NN] = NE;
    __syncthreads();
    for (int i = t; i < cnt; i += 256) {
        int e = (i < CAP) ? es[i] : ebuf[base + i];
        int r = atomicAdd(&cur[e >> 20], 1);  // LDS atomic
        col[base + r] = e & 0xFFFFF;
    }
    // fused quant: qA[g,:] = fp16(dinv[g] * emb[g,:])   (EMB=32 ch -> 8 float4/node)
    for (int i = t; i < 128 * 8; i += 256) {
        int ln = i >> 3;
        int g = b * 128 + ln;
        if (g < NN) {
            float4 v = emb[(size_t)g * 8 + (i & 7)];
            float d = dl[ln];
            v.x *= d; v.y *= d; v.z *= d; v.w *= d;
            qA[(size_t)g * 8 + (i & 7)] = f4_to_h4(v);
        }
    }
}

// ---------------- aggregation core (fp16 gather, f32 accum, int4 col loads) ----------------

__device__ inline void acc8(float* a, uint4 u) {
    const __half2* hp = (const __half2*)&u;
#pragma unroll
    for (int q = 0; q < 4; ++q) {
        float2 f = __half22float2(hp[q]);
        a[2 * q]     += f.x;
        a[2 * q + 1] += f.y;
    }
}

// Accumulate node's in-neighbors (+self) into a[8] for channel-group cg (TPN groups/row).
template<int TPN>
__device__ inline void agg_node(float* a, const uint4* __restrict__ h,
                                const int* __restrict__ col, int node, int beg, int end, int cg) {
    acc8(a, h[(size_t)node * TPN + cg]);  // self-loop term
    int j = beg;
    for (; j < end && (j & 3); ++j) acc8(a, h[(size_t)col[j] * TPN + cg]);
    for (; j + 8 <= end; j += 8) {
        int4 c0 = *(const int4*)(col + j);
        int4 c1 = *(const int4*)(col + j + 4);
        uint4 u0 = h[(size_t)c0.x * TPN + cg];
        uint4 u1 = h[(size_t)c0.y * TPN + cg];
        uint4 u2 = h[(size_t)c0.z * TPN + cg];
        uint4 u3 = h[(size_t)c0.w * TPN + cg];
        uint4 u4 = h[(size_t)c1.x * TPN + cg];
        uint4 u5 = h[(size_t)c1.y * TPN + cg];
        uint4 u6 = h[(size_t)c1.z * TPN + cg];
        uint4 u7 = h[(size_t)c1.w * TPN + cg];
        acc8(a, u0); acc8(a, u1); acc8(a, u2); acc8(a, u3);
        acc8(a, u4); acc8(a, u5); acc8(a, u6); acc8(a, u7);
    }
    for (; j + 4 <= end; j += 4) {
        int4 c0 = *(const int4*)(col + j);
        uint4 u0 = h[(size_t)c0.x * TPN + cg];
        uint4 u1 = h[(size_t)c0.y * TPN + cg];
        uint4 u2 = h[(size_t)c0.z * TPN + cg];
        uint4 u3 = h[(size_t)c0.w * TPN + cg];
        acc8(a, u0); acc8(a, u1); acc8(a, u2); acc8(a, u3);
    }
    for (; j < end; ++j) acc8(a, h[(size_t)col[j] * TPN + cg]);
}

// Standalone agg (layer 2): r = relu(dinv*s + b) -> out (f32) and qout (fp16*dinv).
template<int C, bool BIASRELU, bool WRITE_Q>
__global__ void agg_kernel(const uint4* __restrict__ h, const int* __restrict__ row_ptr,
                           const int* __restrict__ col, const float* __restrict__ dinv,
                           const float* __restrict__ b, float4* __restrict__ out,
                           uint4* __restrict__ qout) {
    constexpr int TPN = C / 8;
    int gid = blockIdx.x * blockDim.x + threadIdx.x;
    int node = gid / TPN;
    int cg = gid % TPN;
    if (node >= NN) return;
    float a[8] = {0, 0, 0, 0, 0, 0, 0, 0};
    agg_node<TPN>(a, h, col, node, row_ptr[node], row_ptr[node + 1], cg);
    float d = dinv[node];
    float r[8];
    if (BIASRELU) {
        const float* bp = b + cg * 8;
#pragma unroll
        for (int q = 0; q < 8; ++q) r[q] = fmaxf(fmaf(d, a[q], bp[q]), 0.f);
    } else {
#pragma unroll
        for (int q = 0; q < 8; ++q) r[q] = d * a[q];
    }
    float4* op = out + (size_t)node * (C / 4) + cg * 2;
    op[0] = make_float4(r[0], r[1], r[2], r[3]);
    op[1] = make_float4(r[4], r[5], r[6], r[7]);
    if (WRITE_Q) {
        uint4 qv;
        __half2* qp = (__half2*)&qv;
#pragma unroll
        for (int q = 0; q < 4; ++q)
            qp[q] = __float22half2_rn(make_float2(r[2 * q] * d, r[2 * q + 1] * d));
        qout[(size_t)node * TPN + cg] = qv;
    }
}

// ---------------- register-tiled matmul (standalone, layer 2) ----------------
template<int IN, int OUT, bool RELU, bool HASBIAS, bool QUANT>
__global__ void mm_kernel(const float* __restrict__ x, const float* __restrict__ W,
                          const float* __restrict__ bias, const float* __restrict__ dinv,
                          float4* __restrict__ out, ushort4* __restrict__ qout) {
    constexpr int CG   = OUT / 4;
    constexpr int RG   = 256 / CG;
    constexpr int ROWS = RG * 4;
    constexpr int P    = IN + 4;
    __shared__ float4 Ws[IN * CG];
    __shared__ float  xs[ROWS * P];

    int tid = threadIdx.x;
    const float4* W4 = (const float4*)W;
    for (int i = tid; i < IN * CG; i += 256) Ws[i] = W4[i];

    int n0 = blockIdx.x * ROWS;
    for (int i = tid; i < ROWS * IN; i += 256) {
        int r = i / IN, c = i & (IN - 1);
        size_t g = (size_t)n0 * IN + i;
        if (g < (size_t)NN * IN) xs[r * P + c] = x[g];
    }
    __syncthreads();

    int cg = tid % CG;
    int rg = tid / CG;

    float4 acc[4] = {{0,0,0,0},{0,0,0,0},{0,0,0,0},{0,0,0,0}};
#pragma unroll 2
    for (int k = 0; k < IN; k += 4) {
        float4 w0 = Ws[(k + 0) * CG + cg];
        float4 w1 = Ws[(k + 1) * CG + cg];
        float4 w2 = Ws[(k + 2) * CG + cg];
        float4 w3 = Ws[(k + 3) * CG + cg];
#pragma unroll
        for (int i = 0; i < 4; ++i) {
            float4 xq = *(const float4*)&xs[(i * RG + rg) * P + k];
            acc[i].x = fmaf(xq.x, w0.x, acc[i].x);
            acc[i].y = fmaf(xq.x, w0.y, acc[i].y);
            acc[i].z = fmaf(xq.x, w0.z, acc[i].z);
            acc[i].w = fmaf(xq.x, w0.w, acc[i].w);
            acc[i].x = fmaf(xq.y, w1.x, acc[i].x);
            acc[i].y = fmaf(xq.y, w1.y, acc[i].y);
            acc[i].z = fmaf(xq.y, w1.z, acc[i].z);
            acc[i].w = fmaf(xq.y, w1.w, acc[i].w);
            acc[i].x = fmaf(xq.z, w2.x, acc[i].x);
            acc[i].y = fmaf(xq.z, w2.y, acc[i].y);
            acc[i].z = fmaf(xq.z, w2.z, acc[i].z);
            acc[i].w = fmaf(xq.z, w2.w, acc[i].w);
            acc[i].x = fmaf(xq.w, w3.x, acc[i].x);
            acc[i].y = fmaf(xq.w, w3.y, acc[i].y);
            acc[i].z = fmaf(xq.w, w3.z, acc[i].z);
            acc[i].w = fmaf(xq.w, w3.w, acc[i].w);
        }
    }

    float4 bb = {0, 0, 0, 0};
    if (HASBIAS) bb = ((const float4*)bias)[cg];
#pragma unroll
    for (int i = 0; i < 4; ++i) {
        int node = n0 + i * RG + rg;
        if (node >= NN) continue;
        float4 r = acc[i];
        if (HASBIAS) { r.x += bb.x; r.y += bb.y; r.z += bb.z; r.w += bb.w; }
        if (RELU) {
            r.x = fmaxf(r.x, 0.f); r.y = fmaxf(r.y, 0.f);
            r.z = fmaxf(r.z, 0.f); r.w = fmaxf(r.w, 0.f);
        }
        if (QUANT) {
            float d = dinv[node];
            r.x *= d; r.y *= d; r.z *= d; r.w *= d;
            qout[(size_t)node * CG + cg] = f4_to_h4(r);
        } else {
            out[(size_t)node * CG + cg] = r;
        }
    }
}

// ---------------- FUSED agg + matmul (agg-first layers 1, 3, 4) ----------------
template<int IN, int OUT, int BS, bool RELU, bool HASBIAS, bool QUANT>
__global__ __launch_bounds__(BS) void aggmm_kernel(
        const uint4* __restrict__ h, const int* __restrict__ row_ptr,
        const int* __restrict__ col, const float* __restrict__ dinv,
        const float* __restrict__ W, const float* __restrict__ bias,
        float4* __restrict__ out, ushort4* __restrict__ qout) {
    constexpr int CG    = OUT / 4;
    constexpr int RG    = BS / CG;
    constexpr int ROWS  = RG * 4;
    constexpr int P     = IN + 4;
    constexpr int TPN_A = IN / 8;      // agg threads per node
    static_assert(ROWS * TPN_A == BS, "agg/mm decomposition mismatch");
    __shared__ float4 Ws[IN * CG];
    __shared__ float  xs[ROWS * P];

    int tid = threadIdx.x;
    const float4* W4 = (const float4*)W;
    for (int i = tid; i < IN * CG; i += BS) Ws[i] = W4[i];

    int n0 = blockIdx.x * ROWS;

    // ---- agg phase: fill xs[ln][cg*8 .. cg*8+8] ----
    {
        int ln = tid / TPN_A;
        int cg = tid % TPN_A;
        int node = n0 + ln;
        float a[8] = {0, 0, 0, 0, 0, 0, 0, 0};
        if (node < NN) {
            agg_node<TPN_A>(a, h, col, node, row_ptr[node], row_ptr[node + 1], cg);
            float d = dinv[node];
#pragma unroll
            for (int q = 0; q < 8; ++q) a[q] *= d;
        }
        float* xp = &xs[ln * P + cg * 8];
        *(float4*)xp       = make_float4(a[0], a[1], a[2], a[3]);
        *(float4*)(xp + 4) = make_float4(a[4], a[5], a[6], a[7]);
    }
    __syncthreads();

    // ---- mm phase ----
    int cg = tid % CG;
    int rg = tid / CG;

    float4 acc[4] = {{0,0,0,0},{0,0,0,0},{0,0,0,0},{0,0,0,0}};
#pragma unroll 2
    for (int k = 0; k < IN; k += 4) {
        float4 w0 = Ws[(k + 0) * CG + cg];
        float4 w1 = Ws[(k + 1) * CG + cg];
        float4 w2 = Ws[(k + 2) * CG + cg];
        float4 w3 = Ws[(k + 3) * CG + cg];
#pragma unroll
        for (int i = 0; i < 4; ++i) {
            float4 xq = *(const float4*)&xs[(i * RG + rg) * P + k];
            acc[i].x = fmaf(xq.x, w0.x, acc[i].x);
            acc[i].y = fmaf(xq.x, w0.y, acc[i].y);
            acc[i].z = fmaf(xq.x, w0.z, acc[i].z);
            acc[i].w = fmaf(xq.x, w0.w, acc[i].w);
            acc[i].x = fmaf(xq.y, w1.x, acc[i].x);
            acc[i].y = fmaf(xq.y, w1.y, acc[i].y);
            acc[i].z = fmaf(xq.y, w1.z, acc[i].z);
            acc[i].w = fmaf(xq.y, w1.w, acc[i].w);
            acc[i].x = fmaf(xq.z, w2.x, acc[i].x);
            acc[i].y = fmaf(xq.z, w2.y, acc[i].y);
            acc[i].z = fmaf(xq.z, w2.z, acc[i].z);
            acc[i].w = fmaf(xq.z, w2.w, acc[i].w);
            acc[i].x = fmaf(xq.w, w3.x, acc[i].x);
            acc[i].y = fmaf(xq.w, w3.y, acc[i].y);
            acc[i].z = fmaf(xq.w, w3.z, acc[i].z);
            acc[i].w = fmaf(xq.w, w3.w, acc[i].w);
        }
    }

    float4 bb = {0, 0, 0, 0};
    if (HASBIAS) bb = ((const float4*)bias)[cg];
#pragma unroll
    for (int i = 0; i < 4; ++i) {
        int node = n0 + i * RG + rg;
        if (node >= NN) continue;
        float4 r = acc[i];
        if (HASBIAS) { r.x += bb.x; r.y += bb.y; r.z += bb.z; r.w += bb.w; }
        if (RELU) {
            r.x = fmaxf(r.x, 0.f); r.y = fmaxf(r.y, 0.f);
            r.z = fmaxf(r.z, 0.f); r.w = fmaxf(r.w, 0.f);
        }
        if (QUANT) {
            float d = dinv[node];
            r.x *= d; r.y *= d; r.z *= d; r.w *= d;
            qout[(size_t)node * CG + cg] = f4_to_h4(r);
        } else {
            out[(size_t)node * CG + cg] = r;
        }
    }
}

// ---------------- launch ----------------

extern "C" void kernel_launch(void* const* d_in, const int* in_sizes, int n_in,
                              void* d_out, int out_size, void* d_ws, size_t ws_size,
                              hipStream_t stream) {
    const int* ei = (const int*)d_in[0];
    const int* src = ei;
    const int* dst = ei + NE;
    const float* emb = (const float*)d_in[1];
    const float* We1 = (const float*)d_in[2]; const float* be1 = (const float*)d_in[3];
    const float* We2 = (const float*)d_in[4]; const float* be2 = (const float*)d_in[5];
    const float* Wd1 = (const float*)d_in[6]; const float* bd1 = (const float*)d_in[7];
    const float* Wd2 = (const float*)d_in[8]; const float* bd2 = (const float*)d_in[9];

    float* outp  = (float*)d_out;
    float* recon = outp;                      // [NN*128]
    float* z     = outp + (size_t)NN * 128;   // [NN*32]

    char* ws = (char*)d_ws;
    size_t off = 0;
    auto alloc = [&](size_t bytes) {
        void* p = ws + off;
        off += (bytes + 255) & ~(size_t)255;
        return p;
    };
    int*     row_ptr = (int*)    alloc((size_t)(NN + 1) * 4);
    int*     col     = (int*)    alloc((size_t)NE * 4);
    float*   dinv    = (float*)  alloc((size_t)NN * 4);
    int*     histT   = (int*)    alloc((size_t)SCNT * 4);
    int*     scanT   = (int*)    alloc((size_t)SCNT * 4);
    int*     blkSum  = (int*)    alloc((size_t)SC_NB * 4);
    int*     ebuf    = (int*)    alloc((size_t)NE * 4);
    ushort4* qA      = (ushort4*)alloc((size_t)NN * 64 * 2);
    ushort4* qB      = (ushort4*)alloc((size_t)NN * 64 * 2);
    float*   fB      = (float*)  alloc((size_t)NN * 64 * 4);
    (void)ws_size; (void)in_sizes; (void)n_in; (void)out_size;

    // --- CSR build (bucketed, no global atomics) + fused emb quant ---
    bhistA_kernel<<<NBLK_A, 1024, 0, stream>>>(dst, histT);
    scan1g_kernel<<<SC_NB, 256, 0, stream>>>(histT, scanT, blkSum);
    scan2g_kernel<<<1, 256, 0, stream>>>(blkSum);
    bscatB_kernel<<<NBLK_A, 1024, 0, stream>>>(src, dst, scanT, blkSum, ebuf);
    csrC_kernel<<<NB, 256, 0, stream>>>(ebuf, scanT, blkSum, row_ptr, col, dinv,
                                        (const float4*)emb, qA);

    // --- layer 1 (fused agg+mm, 256 thr): x1 = relu((dinv*(q1+Σ))@We1 + be1) -> fB ---
    aggmm_kernel<32, 64, 256, true, true, false><<<(NN + 63) / 64, 256, 0, stream>>>(
        (const uint4*)qA, row_ptr, col, dinv, We1, be1, (float4*)fB, nullptr);

    // --- layer 2 (transform-first): h2 = fp16(dinv*(x1@We2)); z = relu(dinv*(h2+Σ)+be2); q3 = fp16(dinv*z) ---
    mm_kernel<64, 32, false, false, true><<<(NN + 127) / 128, 256, 0, stream>>>(
        fB, We2, nullptr, dinv, nullptr, qB);
    agg_kernel<32, true, true><<<(NN * 4 + 255) / 256, 256, 0, stream>>>(
        (const uint4*)qB, row_ptr, col, dinv, be2, (float4*)z, (uint4*)qA);

    // --- layer 3 (fused agg+mm, 256 thr): q4 = fp16(dinv*relu((dinv*(q3+Σ))@Wd1 + bd1)) ---
    aggmm_kernel<32, 64, 256, true, true, true><<<(NN + 63) / 64, 256, 0, stream>>>(
        (const uint4*)qA, row_ptr, col, dinv, Wd1, bd1, nullptr, (ushort4*)qB);

    // --- layer 4 (fused agg+mm, 512 thr): recon = (dinv*(q4+Σ))@Wd2 + bd2 ---
    aggmm_kernel<64, 128, 512, false, true, false><<<(NN + 63) / 64, 512, 0, stream>>>(
        (const uint4*)qB, row_ptr, col, dinv, Wd2, bd2, (float4*)recon, nullptr);
}